// Round 1
// 148.357 us; speedup vs baseline: 1.0397x; 1.0397x over previous
//
#include <hip/hip_runtime.h>
#include <hip/hip_fp16.h>
#include <math.h>

constexpr int B = 16, S = 2048, D = 128, H = 8, NM = 4;
constexpr int KS = 4;          // K-split for G kernel (grid.y)
constexpr int TS = S / KS;     // 512 t per block
constexpr int BK = 64;         // t per staged iteration
constexpr int BKP = 88;        // padded LDS row (f16) = 176 B: 16B-aligned, conflict-even

typedef _Float16 f16x8 __attribute__((ext_vector_type(8)));
typedef _Float16 f16x2 __attribute__((ext_vector_type(2)));
typedef float   f32x16 __attribute__((ext_vector_type(16)));

union PackH { __half2 h2[2]; uint2 u2; };

// ---------------------------------------------------------------------------
// A1: per (b, 128-row t-tile): stage x tile in LDS; f = sigmoid(x@Wf+bf) -> fw;
// fp16 transposed x -> xT[b][i][t]. (fp16 instead of bf16: feeds packed-f16
// scaling + f16 MFMA in gemmG; better mantissa than bf16 for O(1) data.)
// ---------------------------------------------------------------------------
__global__ __launch_bounds__(256, 2) void a1_kernel(
    const float* __restrict__ x, const float* __restrict__ Wf,
    const float* __restrict__ bfv, float* __restrict__ fw,
    ushort* __restrict__ xTu)
{
    __shared__ float sX[128][132];   // 67.6 KB, +4 pad
    __shared__ float sWf[D * H];     // 4 KB

    const int b  = blockIdx.x >> 4;
    const int t0 = (blockIdx.x & 15) << 7;
    const int tid = threadIdx.x;

    for (int e = tid; e < D * H; e += 256) sWf[e] = Wf[e];

    #pragma unroll
    for (int q = 0; q < 16; ++q) {
        const int e = q * 256 + tid;
        const int row = e >> 5, c4 = (e & 31) * 4;
        *(float4*)&sX[row][c4] =
            *(const float4*)&x[((size_t)(b * S) + t0 + row) * D + c4];
    }
    __syncthreads();

    // ---- f projection: thread pair (r, d-half) ----
    {
        const int r = tid >> 1, dh = tid & 1;
        float acch[8] = {0.f,0.f,0.f,0.f,0.f,0.f,0.f,0.f};
        for (int d4 = 0; d4 < 64; d4 += 4) {
            const int d = dh * 64 + d4;
            const float4 xv = *(const float4*)&sX[r][d];
            const float xc[4] = {xv.x, xv.y, xv.z, xv.w};
            #pragma unroll
            for (int c = 0; c < 4; ++c) {
                const float4 wa = *(const float4*)&sWf[(d + c) * 8];
                const float4 wb = *(const float4*)&sWf[(d + c) * 8 + 4];
                acch[0] += xc[c] * wa.x; acch[1] += xc[c] * wa.y;
                acch[2] += xc[c] * wa.z; acch[3] += xc[c] * wa.w;
                acch[4] += xc[c] * wb.x; acch[5] += xc[c] * wb.y;
                acch[6] += xc[c] * wb.z; acch[7] += xc[c] * wb.w;
            }
        }
        #pragma unroll
        for (int hh = 0; hh < 8; ++hh) {
            const float tot = acch[hh] + __shfl_xor(acch[hh], 1);
            if (dh == 0) {
                const float z = tot + bfv[hh];
                fw[((size_t)(b * H + hh)) * S + t0 + r] = 1.f / (1.f + expf(-z));
            }
        }
    }

    // ---- transposed fp16 write: thread (i, t-half) ----
    {
        const int i = tid >> 1, th = tid & 1;
        ushort* dst = xTu + (size_t)(b * D + i) * S + t0 + th * 64;
        #pragma unroll
        for (int tq = 0; tq < 16; ++tq) {
            const int t = th * 64 + tq * 4;
            const float f0 = sX[t + 0][i], f1 = sX[t + 1][i];
            const float f2 = sX[t + 2][i], f3 = sX[t + 3][i];
            PackH pk;
            pk.h2[0] = __float22half2_rn(make_float2(f0, f1));
            pk.h2[1] = __float22half2_rn(make_float2(f2, f3));
            *(uint2*)&dst[tq * 4] = pk.u2;
        }
    }
}

// ---------------------------------------------------------------------------
// gemmG (+inline suffix scan): per (bh, ks):
//   scan: a_t = w_t * prod_{u>t} f_u over full S; store sqrt(a_t) as f16x2
//         pairs (a_t >= 0 always: sigmoid>0, router uniform[0,1]).
//   GEMM: G_part = Y^T Y with Y = diag(sqrt(a)) X, via f16 MFMA 32x32x16.
//         Single scaled LDS tile (double-buffered, 1 barrier/iter), packed
//         v_pk_mul_f16 scaling, v_dot2_f32_f16 for s_vec partials,
//         next-iter global loads issued before the barrier.
// ---------------------------------------------------------------------------
__global__ __launch_bounds__(256, 2) void gemmG_kernel(
    const ushort* __restrict__ xTu, const float* __restrict__ fw,
    const float* __restrict__ router, const int* __restrict__ mem_id,
    float* __restrict__ Gp, float* __restrict__ svp,
    float* __restrict__ fallp, float* __restrict__ sumap)
{
    __shared__ ushort sY[2][128][BKP];   // 45 KB, double-buffered scaled tile
    __shared__ f16x2  sQA[TS / 2];       // 1 KB  sqrt(a) pairs
    __shared__ float  sRed[256];         // 1 KB
    __shared__ float  sC[257];           // 1 KB
    __shared__ float  sR4[4];

    const int bh = blockIdx.x;
    const int b  = bh >> 3;
    const int ks = blockIdx.y;
    const int tid = threadIdx.x;

    // ---------------- inline scan ----------------
    {
        float f[8];
        const float* frow = fw + (size_t)bh * S + tid * 8;
        const float4 fa = *(const float4*)frow;
        const float4 fb = *(const float4*)(frow + 4);
        f[0]=fa.x; f[1]=fa.y; f[2]=fa.z; f[3]=fa.w;
        f[4]=fb.x; f[5]=fb.y; f[6]=fb.z; f[7]=fb.w;

        float p = f[0];
        #pragma unroll
        for (int u = 1; u < 8; ++u) p *= f[u];
        sC[tid] = p;
        __syncthreads();

        for (int off = 1; off < 256; off <<= 1) {
            const float v = (tid + off < 256) ? sC[tid + off] : 1.f;
            __syncthreads();
            sC[tid] *= v;
            __syncthreads();
        }
        const float E = (tid < 255) ? sC[tid + 1] : 1.f;
        const int mid = mem_id[0];

        float aa[8];
        float s = 1.f;
        #pragma unroll
        for (int u = 7; u >= 0; --u) { aa[u] = s * E; s *= f[u]; }

        float avv[8];
        float lsum = 0.f;
        #pragma unroll
        for (int u = 0; u < 8; ++u) {
            const int t = tid * 8 + u;
            const float w = router[((size_t)(b * S) + t) * NM + mid];
            avv[u] = aa[u] * w;
            lsum += avv[u];
        }
        const bool mine = (tid >= ks * 64) && (tid < (ks + 1) * 64);
        if (mine) {
            const int tl = tid - ks * 64;        // 0..63, owns 8 t's
            #pragma unroll
            for (int pq = 0; pq < 4; ++pq) {
                f16x2 qp;
                qp.x = (_Float16)sqrtf(avv[2 * pq]);
                qp.y = (_Float16)sqrtf(avv[2 * pq + 1]);
                sQA[tl * 4 + pq] = qp;
            }
        }
        if (ks == 0) {
            for (int off = 32; off; off >>= 1) lsum += __shfl_down(lsum, off);
            if ((tid & 63) == 0) sR4[tid >> 6] = lsum;
            __syncthreads();
            if (tid == 0) {
                sumap[bh] = sR4[0] + sR4[1] + sR4[2] + sR4[3];
                fallp[bh] = sC[0];
            }
        }
    }
    __syncthreads();

    // ---------------- MFMA main loop ----------------
    const int th = tid >> 7;             // 32-t half within the 64-t chunk
    const int i  = tid & 127;            // feature row
    const ushort* xrow = xTu + (size_t)(b * D + i) * S + ks * TS;

    const int lane = tid & 63, wid = tid >> 6;
    const int wrow = wid >> 1, wcol = wid & 1;
    const int m = lane & 31, half = lane >> 5;

    float svacc = 0.f;
    f32x16 acc00 = {}, acc01 = {}, acc10 = {}, acc11 = {};

    uint4 r[4];
    #pragma unroll
    for (int u = 0; u < 4; ++u)
        r[u] = *(const uint4*)(xrow + th * 32 + u * 8);

    for (int it = 0; it < TS / BK; ++it) {
        const int tloc = it * BK + th * 32;
        const int cb = it & 1;

        // sqrt(a) for this thread's 32 t's (wave-uniform addr -> broadcast)
        uint4 q4[4];
        #pragma unroll
        for (int u = 0; u < 4; ++u)
            q4[u] = *(const uint4*)&sQA[tloc / 2 + u * 4];

        // scale Y = sqrt(a) * x in packed f16; s_vec partial via dot2
        #pragma unroll
        for (int u = 0; u < 4; ++u) {
            const f16x2* xp = (const f16x2*)&r[u];
            const f16x2* qp = (const f16x2*)&q4[u];
            union { f16x2 h[4]; uint4 uu; } ov;
            #pragma unroll
            for (int q = 0; q < 4; ++q) {
                const f16x2 y = xp[q] * qp[q];
                ov.h[q] = y;
#if __has_builtin(__builtin_amdgcn_fdot2)
                svacc = __builtin_amdgcn_fdot2(y, qp[q], svacc, false);
#else
                svacc += (float)y.x * (float)qp[q].x + (float)y.y * (float)qp[q].y;
#endif
            }
            *(uint4*)&sY[cb][i][th * 32 + u * 8] = ov.uu;
        }

        // issue next iter's global loads before the barrier (latency hidden
        // under this iter's MFMA phase)
        if (it + 1 < TS / BK) {
            #pragma unroll
            for (int u = 0; u < 4; ++u)
                r[u] = *(const uint4*)(xrow + (it + 1) * BK + th * 32 + u * 8);
        }

        __syncthreads();   // writes(it) done; mfma(it-1) on other buffer done

        #pragma unroll
        for (int kstep = 0; kstep < 4; ++kstep) {
            const int koff = kstep * 16 + half * 8;
            const f16x8 a0 = *(const f16x8*)&sY[cb][wrow * 64 +      m][koff];
            const f16x8 a1 = *(const f16x8*)&sY[cb][wrow * 64 + 32 + m][koff];
            const f16x8 b0 = *(const f16x8*)&sY[cb][wcol * 64 +      m][koff];
            const f16x8 b1 = *(const f16x8*)&sY[cb][wcol * 64 + 32 + m][koff];
            acc00 = __builtin_amdgcn_mfma_f32_32x32x16_f16(a0, b0, acc00, 0, 0, 0);
            acc01 = __builtin_amdgcn_mfma_f32_32x32x16_f16(a0, b1, acc01, 0, 0, 0);
            acc10 = __builtin_amdgcn_mfma_f32_32x32x16_f16(a1, b0, acc10, 0, 0, 0);
            acc11 = __builtin_amdgcn_mfma_f32_32x32x16_f16(a1, b1, acc11, 0, 0, 0);
        }
    }

    // C/D layout (m74/m101): col = lane&31, row = (r&3)+8*(r>>2)+4*half
    float* gp = Gp + (size_t)(ks * B * H + bh) * (D * D);
    #pragma unroll
    for (int rg = 0; rg < 16; ++rg) {
        const int rowl = (rg & 3) + 8 * (rg >> 2) + 4 * half;
        gp[(wrow * 64 +      rowl) * D + wcol * 64 +      m] = acc00[rg];
        gp[(wrow * 64 +      rowl) * D + wcol * 64 + 32 + m] = acc01[rg];
        gp[(wrow * 64 + 32 + rowl) * D + wcol * 64 +      m] = acc10[rg];
        gp[(wrow * 64 + 32 + rowl) * D + wcol * 64 + 32 + m] = acc11[rg];
    }

    sRed[tid] = svacc;
    __syncthreads();
    if (tid < 128)
        svp[((size_t)ks * (B * H) + bh) * D + tid] = sRed[tid] + sRed[tid + 128];
}

// ---------------------------------------------------------------------------
// final: per (bh, col-half): C = Wk^T (G Wv) + u*bv^T + bk*w^T + suma*bk*bv^T
// + fall*M0. fp32 VALU; G symmetry -> all LDS reads row-major float4.
// ---------------------------------------------------------------------------
__global__ __launch_bounds__(256, 1) void final_kernel(
    const float* __restrict__ Gp, const float* __restrict__ Wk,
    const float* __restrict__ bk, const float* __restrict__ Wv,
    const float* __restrict__ bv, const float* __restrict__ svp,
    const float* __restrict__ fallp, const float* __restrict__ sumap,
    const float* __restrict__ M0, float* __restrict__ out)
{
    __shared__ float sA[128][132];
    __shared__ float sB[128][132];
    __shared__ float sSv[128];

    const int bh = blockIdx.x >> 1, hf = blockIdx.x & 1;
    const int h  = bh & 7;
    const int tid = threadIdx.x;

    #pragma unroll
    for (int q = 0; q < 16; ++q) {
        const int flat = q * 256 + tid;
        const int row = flat >> 5, c4 = (flat & 31) * 4;
        const size_t off = (size_t)bh * (D * D) + row * D + c4;
        float4 g = *(const float4*)&Gp[off];
        #pragma unroll
        for (int k = 1; k < KS; ++k) {
            const float4 g2 = *(const float4*)&Gp[(size_t)k * B * H * D * D + off];
            g.x += g2.x; g.y += g2.y; g.z += g2.z; g.w += g2.w;
        }
        *(float4*)&sA[row][c4] = g;
    }
    #pragma unroll
    for (int q = 0; q < 8; ++q) {
        const int flat = q * 256 + tid;
        const int l = flat >> 4, c4 = (flat & 15) * 4;
        *(float4*)&sB[l][c4] =
            *(const float4*)&Wv[(size_t)l * (D * H) + h * D + hf * 64 + c4];
    }
    if (tid < 128) {
        float s = 0.f;
        #pragma unroll
        for (int k = 0; k < KS; ++k)
            s += svp[((size_t)k * (B * H) + bh) * D + tid];
        sSv[tid] = s;
    }
    __syncthreads();

    const int r0 = (tid >> 3) * 4, c0 = (tid & 7) * 8;

    float P[4][8] = {};
    float wv8[8] = {};
    for (int l = 0; l < 128; ++l) {
        const float4 g  = *(const float4*)&sA[l][r0];
        const float4 w0 = *(const float4*)&sB[l][c0];
        const float4 w1 = *(const float4*)&sB[l][c0 + 4];
        const float sl = sSv[l];
        const float gg[4] = {g.x, g.y, g.z, g.w};
        const float ww[8] = {w0.x,w0.y,w0.z,w0.w,w1.x,w1.y,w1.z,w1.w};
        #pragma unroll
        for (int dr = 0; dr < 4; ++dr)
            #pragma unroll
            for (int dc = 0; dc < 8; ++dc) P[dr][dc] += gg[dr] * ww[dc];
        #pragma unroll
        for (int dc = 0; dc < 8; ++dc) wv8[dc] += sl * ww[dc];
    }
    __syncthreads();

    #pragma unroll
    for (int dr = 0; dr < 4; ++dr) {
        *(float4*)&sA[r0 + dr][c0]     = make_float4(P[dr][0], P[dr][1], P[dr][2], P[dr][3]);
        *(float4*)&sA[r0 + dr][c0 + 4] = make_float4(P[dr][4], P[dr][5], P[dr][6], P[dr][7]);
    }
    #pragma unroll
    for (int q = 0; q < 16; ++q) {
        const int flat = q * 256 + tid;
        const int k = flat >> 5, c4 = (flat & 31) * 4;
        *(float4*)&sB[k][c4] = *(const float4*)&Wk[(size_t)k * (D * H) + h * D + c4];
    }
    __syncthreads();

    float C[4][8] = {};
    float u4[4] = {};
    for (int k = 0; k < 128; ++k) {
        const float4 wk = *(const float4*)&sB[k][r0];
        const float4 p0 = *(const float4*)&sA[k][c0];
        const float4 p1 = *(const float4*)&sA[k][c0 + 4];
        const float svk = sSv[k];
        const float wkk[4] = {wk.x, wk.y, wk.z, wk.w};
        const float pp[8] = {p0.x,p0.y,p0.z,p0.w,p1.x,p1.y,p1.z,p1.w};
        #pragma unroll
        for (int di = 0; di < 4; ++di) {
            #pragma unroll
            for (int dc = 0; dc < 8; ++dc) C[di][dc] += wkk[di] * pp[dc];
            u4[di] += wkk[di] * svk;
        }
    }

    const float fallv = fallp[bh], sumav = sumap[bh];
    float bkv[4], bvv[8];
    #pragma unroll
    for (int di = 0; di < 4; ++di) bkv[di] = bk[h * D + r0 + di];
    #pragma unroll
    for (int dc = 0; dc < 8; ++dc) bvv[dc] = bv[h * D + hf * 64 + c0 + dc];

    const float* m0p = M0 + (size_t)bh * (D * D);
    float* op = out + (size_t)bh * (D * D);
    #pragma unroll
    for (int di = 0; di < 4; ++di)
        #pragma unroll
        for (int dc = 0; dc < 8; ++dc) {
            const size_t idx = (size_t)(r0 + di) * D + hf * 64 + c0 + dc;
            op[idx] = C[di][dc] + u4[di] * bvv[dc] + bkv[di] * wv8[dc]
                    + sumav * bkv[di] * bvv[dc] + fallv * m0p[idx];
        }
}

extern "C" void kernel_launch(void* const* d_in, const int* in_sizes, int n_in,
                              void* d_out, int out_size, void* d_ws, size_t ws_size,
                              hipStream_t stream) {
    const float* x      = (const float*)d_in[0];
    const float* M0     = (const float*)d_in[1];
    const float* router = (const float*)d_in[2];
    const int*   mem_id = (const int*)d_in[3];
    const float* Wk     = (const float*)d_in[4];
    const float* bk     = (const float*)d_in[5];
    const float* Wv     = (const float*)d_in[6];
    const float* bv     = (const float*)d_in[7];
    const float* Wf     = (const float*)d_in[8];
    const float* bf     = (const float*)d_in[9];
    float* out = (float*)d_out;

    char* ws = (char*)d_ws;
    ushort* xTu  = (ushort*)ws;                               // 8 MB   f16 x^T
    float*  fw   = (float*)(ws + (8u << 20));                 // 1 MB   f gates
    float*  svp  = (float*)(ws + (9u << 20));                 // 256 KB s_vec partials
    float*  fall = (float*)(ws + (9u << 20) + (512u << 10));  // 512 B
    float*  suma = (float*)(ws + (9u << 20) + (512u << 10) + 4096);
    float*  Gp   = (float*)(ws + (10u << 20));                // 32 MB  G partials

    a1_kernel<<<256, 256, 0, stream>>>(x, Wf, bf, fw, xTu);
    gemmG_kernel<<<dim3(B * H, KS), 256, 0, stream>>>(xTu, fw, router, mem_id,
                                                      Gp, svp, fall, suma);
    final_kernel<<<2 * B * H, 256, 0, stream>>>(Gp, Wk, bk, Wv, bv, svp,
                                                fall, suma, M0, out);
}

// Round 4
// 136.613 us; speedup vs baseline: 1.1290x; 1.0860x over previous
//
#include <hip/hip_runtime.h>
#include <hip/hip_fp16.h>
#include <math.h>

constexpr int B = 16, S = 2048, D = 128, H = 8, NM = 4;
constexpr int KS = 4;          // K-split for G kernel (grid.y)
constexpr int TS = S / KS;     // 512 t per block
constexpr int BK = 64;         // t per staged iteration
constexpr int NT = TS / BK;    // 8 tiles per block
constexpr int BKP = 88;        // padded LDS row (f16) = 176 B: 16B-aligned, conflict-even

typedef _Float16 f16x8 __attribute__((ext_vector_type(8)));
typedef _Float16 f16x2 __attribute__((ext_vector_type(2)));
typedef float   f32x16 __attribute__((ext_vector_type(16)));

union PackH { __half2 h2[2]; uint2 u2; };

// ---------------------------------------------------------------------------
// A1: per (b, 128-row t-tile): stage x tile in LDS; f = sigmoid(x@Wf+bf) -> fw;
// fp16 transposed x -> xT[b][i][t].
// ---------------------------------------------------------------------------
__global__ __launch_bounds__(256, 2) void a1_kernel(
    const float* __restrict__ x, const float* __restrict__ Wf,
    const float* __restrict__ bfv, float* __restrict__ fw,
    ushort* __restrict__ xTu)
{
    __shared__ float sX[128][132];   // 67.6 KB, +4 pad
    __shared__ float sWf[D * H];     // 4 KB

    const int b  = blockIdx.x >> 4;
    const int t0 = (blockIdx.x & 15) << 7;
    const int tid = threadIdx.x;

    for (int e = tid; e < D * H; e += 256) sWf[e] = Wf[e];

    #pragma unroll
    for (int q = 0; q < 16; ++q) {
        const int e = q * 256 + tid;
        const int row = e >> 5, c4 = (e & 31) * 4;
        *(float4*)&sX[row][c4] =
            *(const float4*)&x[((size_t)(b * S) + t0 + row) * D + c4];
    }
    __syncthreads();

    // ---- f projection: thread pair (r, d-half) ----
    {
        const int r = tid >> 1, dh = tid & 1;
        float acch[8] = {0.f,0.f,0.f,0.f,0.f,0.f,0.f,0.f};
        for (int d4 = 0; d4 < 64; d4 += 4) {
            const int d = dh * 64 + d4;
            const float4 xv = *(const float4*)&sX[r][d];
            const float xc[4] = {xv.x, xv.y, xv.z, xv.w};
            #pragma unroll
            for (int c = 0; c < 4; ++c) {
                const float4 wa = *(const float4*)&sWf[(d + c) * 8];
                const float4 wb = *(const float4*)&sWf[(d + c) * 8 + 4];
                acch[0] += xc[c] * wa.x; acch[1] += xc[c] * wa.y;
                acch[2] += xc[c] * wa.z; acch[3] += xc[c] * wa.w;
                acch[4] += xc[c] * wb.x; acch[5] += xc[c] * wb.y;
                acch[6] += xc[c] * wb.z; acch[7] += xc[c] * wb.w;
            }
        }
        #pragma unroll
        for (int hh = 0; hh < 8; ++hh) {
            const float tot = acch[hh] + __shfl_xor(acch[hh], 1);
            if (dh == 0) {
                const float z = tot + bfv[hh];
                fw[((size_t)(b * H + hh)) * S + t0 + r] = 1.f / (1.f + expf(-z));
            }
        }
    }

    // ---- transposed fp16 write: thread (i, t-half) ----
    {
        const int i = tid >> 1, th = tid & 1;
        ushort* dst = xTu + (size_t)(b * D + i) * S + t0 + th * 64;
        #pragma unroll
        for (int tq = 0; tq < 16; ++tq) {
            const int t = th * 64 + tq * 4;
            const float f0 = sX[t + 0][i], f1 = sX[t + 1][i];
            const float f2 = sX[t + 2][i], f3 = sX[t + 3][i];
            PackH pk;
            pk.h2[0] = __float22half2_rn(make_float2(f0, f1));
            pk.h2[1] = __float22half2_rn(make_float2(f2, f3));
            *(uint2*)&dst[tq * 4] = pk.u2;
        }
    }
}

// ---------------------------------------------------------------------------
// gemmG (+inline suffix scan): per (bh, ks):
//   scan: a_t = w_t * prod_{u>t} f_u; store sqrt(a_t) as f16x2 pairs.
//   PREFIX-ZERO SKIP: the suffix product P_t is monotone increasing in t and
//   underflows fp32/fp16->0 for all but the tail of S, so tiles whose stored
//   fp16 sqrt(a) are ALL exactly 0 form a PREFIX. Starting the (round-1
//   proven) main loop at the first active tile is bitwise identical to
//   processing everything. Blocks with no active tile skip the 64 KB Gp
//   store and publish gval=0; final sums only gval=1 partials.
//   GEMM: G_part = Y^T Y with Y = diag(sqrt(a)) X, f16 MFMA 32x32x16,
//   double-buffered LDS, 1 barrier per processed tile.
// ---------------------------------------------------------------------------
__global__ __launch_bounds__(256, 2) void gemmG_kernel(
    const ushort* __restrict__ xTu, const float* __restrict__ fw,
    const float* __restrict__ router, const int* __restrict__ mem_id,
    float* __restrict__ Gp, float* __restrict__ svp,
    float* __restrict__ fallp, float* __restrict__ sumap,
    int* __restrict__ gval)
{
    __shared__ ushort sY[2][128][BKP];   // 45 KB, double-buffered scaled tile
    __shared__ f16x2  sQA[TS / 2];       // 1 KB  sqrt(a) pairs
    __shared__ float  sRed[256];         // 1 KB
    __shared__ float  sC[257];           // 1 KB
    __shared__ float  sR4[4];
    __shared__ int    sNZ[NT];           // per-tile nonzero flags

    const int bh = blockIdx.x;
    const int b  = bh >> 3;
    const int ks = blockIdx.y;
    const int tid = threadIdx.x;

    if (tid < NT) sNZ[tid] = 0;

    // ---------------- inline scan ----------------
    {
        float f[8];
        const float* frow = fw + (size_t)bh * S + tid * 8;
        const float4 fa = *(const float4*)frow;
        const float4 fb = *(const float4*)(frow + 4);
        f[0]=fa.x; f[1]=fa.y; f[2]=fa.z; f[3]=fa.w;
        f[4]=fb.x; f[5]=fb.y; f[6]=fb.z; f[7]=fb.w;

        float p = f[0];
        #pragma unroll
        for (int u = 1; u < 8; ++u) p *= f[u];
        sC[tid] = p;
        __syncthreads();

        for (int off = 1; off < 256; off <<= 1) {
            const float v = (tid + off < 256) ? sC[tid + off] : 1.f;
            __syncthreads();
            sC[tid] *= v;
            __syncthreads();
        }
        const float E = (tid < 255) ? sC[tid + 1] : 1.f;
        const int mid = mem_id[0];

        float aa[8];
        float s = 1.f;
        #pragma unroll
        for (int u = 7; u >= 0; --u) { aa[u] = s * E; s *= f[u]; }

        float avv[8];
        float lsum = 0.f;
        #pragma unroll
        for (int u = 0; u < 8; ++u) {
            const int t = tid * 8 + u;
            const float w = router[((size_t)(b * S) + t) * NM + mid];
            avv[u] = aa[u] * w;
            lsum += avv[u];
        }
        const bool mine = (tid >= ks * 64) && (tid < (ks + 1) * 64);
        if (mine) {
            const int tl = tid - ks * 64;        // 0..63, owns 8 t's
            bool nz = false;
            #pragma unroll
            for (int pq = 0; pq < 4; ++pq) {
                f16x2 qp;
                qp.x = (_Float16)sqrtf(avv[2 * pq]);
                qp.y = (_Float16)sqrtf(avv[2 * pq + 1]);
                sQA[tl * 4 + pq] = qp;
                nz = nz || (qp.x != (_Float16)0.f) || (qp.y != (_Float16)0.f);
            }
            if (nz) sNZ[tl >> 3] = 1;            // benign race: all write 1
        }
        if (ks == 0) {
            for (int off = 32; off; off >>= 1) lsum += __shfl_down(lsum, off);
            if ((tid & 63) == 0) sR4[tid >> 6] = lsum;
            __syncthreads();
            if (tid == 0) {
                sumap[bh] = sR4[0] + sR4[1] + sR4[2] + sR4[3];
                fallp[bh] = sC[0];
            }
        }
    }
    __syncthreads();

    int nzmask = 0;
    #pragma unroll
    for (int tt = 0; tt < NT; ++tt) nzmask |= (sNZ[tt] ? 1 : 0) << tt;
    const int itStart = (nzmask != 0) ? __builtin_ctz(nzmask) : NT;  // uniform

    // ---------------- MFMA main loop (round-1 body, starts at itStart) ------
    const int th = tid >> 7;             // 32-t half within the 64-t chunk
    const int i  = tid & 127;            // feature row
    const ushort* xrow = xTu + (size_t)(b * D + i) * S + ks * TS;

    const int lane = tid & 63, wid = tid >> 6;
    const int wrow = wid >> 1, wcol = wid & 1;
    const int m = lane & 31, half = lane >> 5;

    float svacc = 0.f;
    f32x16 acc00 = {}, acc01 = {}, acc10 = {}, acc11 = {};

    uint4 r[4];
    if (nzmask != 0) {
        #pragma unroll
        for (int u = 0; u < 4; ++u)
            r[u] = *(const uint4*)(xrow + itStart * BK + th * 32 + u * 8);
    }

    for (int it = itStart; it < NT; ++it) {
        const int tloc = it * BK + th * 32;
        const int cb = it & 1;

        // sqrt(a) for this thread's 32 t's (wave-uniform addr -> broadcast)
        uint4 q4[4];
        #pragma unroll
        for (int u = 0; u < 4; ++u)
            q4[u] = *(const uint4*)&sQA[tloc / 2 + u * 4];

        // scale Y = sqrt(a) * x in packed f16; s_vec partial via dot2
        #pragma unroll
        for (int u = 0; u < 4; ++u) {
            const f16x2* xp = (const f16x2*)&r[u];
            const f16x2* qp = (const f16x2*)&q4[u];
            union { f16x2 h[4]; uint4 uu; } ov;
            #pragma unroll
            for (int q = 0; q < 4; ++q) {
                const f16x2 y = xp[q] * qp[q];
                ov.h[q] = y;
#if __has_builtin(__builtin_amdgcn_fdot2)
                svacc = __builtin_amdgcn_fdot2(y, qp[q], svacc, false);
#else
                svacc += (float)y.x * (float)qp[q].x + (float)y.y * (float)qp[q].y;
#endif
            }
            *(uint4*)&sY[cb][i][th * 32 + u * 8] = ov.uu;
        }

        // issue next iter's global loads before the barrier (latency hidden
        // under this iter's MFMA phase)
        if (it + 1 < NT) {
            #pragma unroll
            for (int u = 0; u < 4; ++u)
                r[u] = *(const uint4*)(xrow + (it + 1) * BK + th * 32 + u * 8);
        }

        __syncthreads();   // writes(it) done; mfma(it-1) on other buffer done

        #pragma unroll
        for (int kstep = 0; kstep < 4; ++kstep) {
            const int koff = kstep * 16 + half * 8;
            const f16x8 a0 = *(const f16x8*)&sY[cb][wrow * 64 +      m][koff];
            const f16x8 a1 = *(const f16x8*)&sY[cb][wrow * 64 + 32 + m][koff];
            const f16x8 b0 = *(const f16x8*)&sY[cb][wcol * 64 +      m][koff];
            const f16x8 b1 = *(const f16x8*)&sY[cb][wcol * 64 + 32 + m][koff];
            acc00 = __builtin_amdgcn_mfma_f32_32x32x16_f16(a0, b0, acc00, 0, 0, 0);
            acc01 = __builtin_amdgcn_mfma_f32_32x32x16_f16(a0, b1, acc01, 0, 0, 0);
            acc10 = __builtin_amdgcn_mfma_f32_32x32x16_f16(a1, b0, acc10, 0, 0, 0);
            acc11 = __builtin_amdgcn_mfma_f32_32x32x16_f16(a1, b1, acc11, 0, 0, 0);
        }
    }

    // C/D layout (m74/m101): col = lane&31, row = (r&3)+8*(r>>2)+4*half
    if (nzmask != 0) {
        float* gp = Gp + (size_t)(ks * B * H + bh) * (D * D);
        #pragma unroll
        for (int rg = 0; rg < 16; ++rg) {
            const int rowl = (rg & 3) + 8 * (rg >> 2) + 4 * half;
            gp[(wrow * 64 +      rowl) * D + wcol * 64 +      m] = acc00[rg];
            gp[(wrow * 64 +      rowl) * D + wcol * 64 + 32 + m] = acc01[rg];
            gp[(wrow * 64 + 32 + rowl) * D + wcol * 64 +      m] = acc10[rg];
            gp[(wrow * 64 + 32 + rowl) * D + wcol * 64 + 32 + m] = acc11[rg];
        }
    }
    if (tid == 0) gval[ks * (B * H) + bh] = (nzmask != 0) ? 1 : 0;

    sRed[tid] = svacc;
    __syncthreads();
    if (tid < 128)
        svp[((size_t)ks * (B * H) + bh) * D + tid] = sRed[tid] + sRed[tid + 128];
}

// ---------------------------------------------------------------------------
// final: per (bh, col-half): C = Wk^T (G Wv) + u*bv^T + bk*w^T + suma*bk*bv^T
// + fall*M0. fp32 VALU; G symmetry -> all LDS reads row-major float4.
// Only sums Gp partials whose gval flag is set (others are exact zero).
// ---------------------------------------------------------------------------
__global__ __launch_bounds__(256, 1) void final_kernel(
    const float* __restrict__ Gp, const float* __restrict__ Wk,
    const float* __restrict__ bk, const float* __restrict__ Wv,
    const float* __restrict__ bv, const float* __restrict__ svp,
    const float* __restrict__ fallp, const float* __restrict__ sumap,
    const float* __restrict__ M0, float* __restrict__ out,
    const int* __restrict__ gval)
{
    __shared__ float sA[128][132];
    __shared__ float sB[128][132];
    __shared__ float sSv[128];

    const int bh = blockIdx.x >> 1, hf = blockIdx.x & 1;
    const int h  = bh & 7;
    const int tid = threadIdx.x;

    int kmask = 0;
    #pragma unroll
    for (int k = 0; k < KS; ++k)
        kmask |= (gval[k * (B * H) + bh] ? 1 : 0) << k;

    #pragma unroll
    for (int q = 0; q < 16; ++q) {
        const int flat = q * 256 + tid;
        const int row = flat >> 5, c4 = (flat & 31) * 4;
        const size_t off = (size_t)bh * (D * D) + row * D + c4;
        float4 g = make_float4(0.f, 0.f, 0.f, 0.f);
        #pragma unroll
        for (int k = 0; k < KS; ++k) {
            if ((kmask >> k) & 1) {
                const float4 g2 = *(const float4*)&Gp[(size_t)k * B * H * D * D + off];
                g.x += g2.x; g.y += g2.y; g.z += g2.z; g.w += g2.w;
            }
        }
        *(float4*)&sA[row][c4] = g;
    }
    #pragma unroll
    for (int q = 0; q < 8; ++q) {
        const int flat = q * 256 + tid;
        const int l = flat >> 4, c4 = (flat & 15) * 4;
        *(float4*)&sB[l][c4] =
            *(const float4*)&Wv[(size_t)l * (D * H) + h * D + hf * 64 + c4];
    }
    if (tid < 128) {
        float s = 0.f;
        #pragma unroll
        for (int k = 0; k < KS; ++k)
            s += svp[((size_t)k * (B * H) + bh) * D + tid];
        sSv[tid] = s;
    }
    __syncthreads();

    const int r0 = (tid >> 3) * 4, c0 = (tid & 7) * 8;

    float P[4][8] = {};
    float wv8[8] = {};
    for (int l = 0; l < 128; ++l) {
        const float4 g  = *(const float4*)&sA[l][r0];
        const float4 w0 = *(const float4*)&sB[l][c0];
        const float4 w1 = *(const float4*)&sB[l][c0 + 4];
        const float sl = sSv[l];
        const float gg[4] = {g.x, g.y, g.z, g.w};
        const float ww[8] = {w0.x,w0.y,w0.z,w0.w,w1.x,w1.y,w1.z,w1.w};
        #pragma unroll
        for (int dr = 0; dr < 4; ++dr)
            #pragma unroll
            for (int dc = 0; dc < 8; ++dc) P[dr][dc] += gg[dr] * ww[dc];
        #pragma unroll
        for (int dc = 0; dc < 8; ++dc) wv8[dc] += sl * ww[dc];
    }
    __syncthreads();

    #pragma unroll
    for (int dr = 0; dr < 4; ++dr) {
        *(float4*)&sA[r0 + dr][c0]     = make_float4(P[dr][0], P[dr][1], P[dr][2], P[dr][3]);
        *(float4*)&sA[r0 + dr][c0 + 4] = make_float4(P[dr][4], P[dr][5], P[dr][6], P[dr][7]);
    }
    #pragma unroll
    for (int q = 0; q < 16; ++q) {
        const int flat = q * 256 + tid;
        const int k = flat >> 5, c4 = (flat & 31) * 4;
        *(float4*)&sB[k][c4] = *(const float4*)&Wk[(size_t)k * (D * H) + h * D + c4];
    }
    __syncthreads();

    float C[4][8] = {};
    float u4[4] = {};
    for (int k = 0; k < 128; ++k) {
        const float4 wk = *(const float4*)&sB[k][r0];
        const float4 p0 = *(const float4*)&sA[k][c0];
        const float4 p1 = *(const float4*)&sA[k][c0 + 4];
        const float svk = sSv[k];
        const float wkk[4] = {wk.x, wk.y, wk.z, wk.w};
        const float pp[8] = {p0.x,p0.y,p0.z,p0.w,p1.x,p1.y,p1.z,p1.w};
        #pragma unroll
        for (int di = 0; di < 4; ++di) {
            #pragma unroll
            for (int dc = 0; dc < 8; ++dc) C[di][dc] += wkk[di] * pp[dc];
            u4[di] += wkk[di] * svk;
        }
    }

    const float fallv = fallp[bh], sumav = sumap[bh];
    float bkv[4], bvv[8];
    #pragma unroll
    for (int di = 0; di < 4; ++di) bkv[di] = bk[h * D + r0 + di];
    #pragma unroll
    for (int dc = 0; dc < 8; ++dc) bvv[dc] = bv[h * D + hf * 64 + c0 + dc];

    const float* m0p = M0 + (size_t)bh * (D * D);
    float* op = out + (size_t)bh * (D * D);
    #pragma unroll
    for (int di = 0; di < 4; ++di)
        #pragma unroll
        for (int dc = 0; dc < 8; ++dc) {
            const size_t idx = (size_t)(r0 + di) * D + hf * 64 + c0 + dc;
            op[idx] = C[di][dc] + u4[di] * bvv[dc] + bkv[di] * wv8[dc]
                    + sumav * bkv[di] * bvv[dc] + fallv * m0p[idx];
        }
}

extern "C" void kernel_launch(void* const* d_in, const int* in_sizes, int n_in,
                              void* d_out, int out_size, void* d_ws, size_t ws_size,
                              hipStream_t stream) {
    const float* x      = (const float*)d_in[0];
    const float* M0     = (const float*)d_in[1];
    const float* router = (const float*)d_in[2];
    const int*   mem_id = (const int*)d_in[3];
    const float* Wk     = (const float*)d_in[4];
    const float* bk     = (const float*)d_in[5];
    const float* Wv     = (const float*)d_in[6];
    const float* bv     = (const float*)d_in[7];
    const float* Wf     = (const float*)d_in[8];
    const float* bf     = (const float*)d_in[9];
    float* out = (float*)d_out;

    char* ws = (char*)d_ws;
    ushort* xTu  = (ushort*)ws;                               // 8 MB   f16 x^T
    float*  fw   = (float*)(ws + (8u << 20));                 // 1 MB   f gates
    float*  svp  = (float*)(ws + (9u << 20));                 // 256 KB s_vec partials
    float*  fall = (float*)(ws + (9u << 20) + (512u << 10));  // 512 B
    float*  suma = (float*)(ws + (9u << 20) + (512u << 10) + 4096);
    int*    gval = (int*)  (ws + (9u << 20) + (512u << 10) + 8192);  // 2 KB flags
    float*  Gp   = (float*)(ws + (10u << 20));                // 32 MB  G partials

    a1_kernel<<<256, 256, 0, stream>>>(x, Wf, bf, fw, xTu);
    gemmG_kernel<<<dim3(B * H, KS), 256, 0, stream>>>(xTu, fw, router, mem_id,
                                                      Gp, svp, fall, suma, gval);
    final_kernel<<<2 * B * H, 256, 0, stream>>>(Gp, Wk, bk, Wv, bv, svp,
                                                fall, suma, M0, out, gval);
}

// Round 5
// 130.935 us; speedup vs baseline: 1.1780x; 1.0434x over previous
//
#include <hip/hip_runtime.h>
#include <hip/hip_fp16.h>
#include <math.h>

constexpr int B = 16, S = 2048, D = 128, H = 8, NM = 4;
constexpr int BK = 64;         // t per staged tile
constexpr int NT = S / BK;     // 32 tiles over full S
constexpr int BKP = 88;        // padded LDS row (f16) = 176 B, 16B-aligned

typedef _Float16 f16x8 __attribute__((ext_vector_type(8)));
typedef _Float16 f16x2 __attribute__((ext_vector_type(2)));
typedef float   f32x16 __attribute__((ext_vector_type(16)));

// ---------------------------------------------------------------------------
// f_kernel: per (b, 128-row t-tile): stage x tile in LDS; f = sigmoid(x@Wf+bf)
// -> fw.  (Transpose/xTu removed: gemmG now stages directly from x.)
// ---------------------------------------------------------------------------
__global__ __launch_bounds__(256, 2) void f_kernel(
    const float* __restrict__ x, const float* __restrict__ Wf,
    const float* __restrict__ bfv, float* __restrict__ fw)
{
    __shared__ float sX[128][132];   // 67.6 KB, +4 pad
    __shared__ float sWf[D * H];     // 4 KB

    const int b  = blockIdx.x >> 4;
    const int t0 = (blockIdx.x & 15) << 7;
    const int tid = threadIdx.x;

    for (int e = tid; e < D * H; e += 256) sWf[e] = Wf[e];

    #pragma unroll
    for (int q = 0; q < 16; ++q) {
        const int e = q * 256 + tid;
        const int row = e >> 5, c4 = (e & 31) * 4;
        *(float4*)&sX[row][c4] =
            *(const float4*)&x[((size_t)(b * S) + t0 + row) * D + c4];
    }
    __syncthreads();

    // ---- f projection: thread pair (r, d-half) ----
    const int r = tid >> 1, dh = tid & 1;
    float acch[8] = {0.f,0.f,0.f,0.f,0.f,0.f,0.f,0.f};
    for (int d4 = 0; d4 < 64; d4 += 4) {
        const int d = dh * 64 + d4;
        const float4 xv = *(const float4*)&sX[r][d];
        const float xc[4] = {xv.x, xv.y, xv.z, xv.w};
        #pragma unroll
        for (int c = 0; c < 4; ++c) {
            const float4 wa = *(const float4*)&sWf[(d + c) * 8];
            const float4 wb = *(const float4*)&sWf[(d + c) * 8 + 4];
            acch[0] += xc[c] * wa.x; acch[1] += xc[c] * wa.y;
            acch[2] += xc[c] * wa.z; acch[3] += xc[c] * wa.w;
            acch[4] += xc[c] * wb.x; acch[5] += xc[c] * wb.y;
            acch[6] += xc[c] * wb.z; acch[7] += xc[c] * wb.w;
        }
    }
    #pragma unroll
    for (int hh = 0; hh < 8; ++hh) {
        const float tot = acch[hh] + __shfl_xor(acch[hh], 1);
        if (dh == 0) {
            const float z = tot + bfv[hh];
            fw[((size_t)(b * H + hh)) * S + t0 + r] = 1.f / (1.f + expf(-z));
        }
    }
}

// ---------------------------------------------------------------------------
// gscan: ONE block per bh (grid B*H). Full-S scan once (was 4x redundant):
//   a_t = w_t * prod_{u>t} f_u; sqrt(a_t) f16 in LDS; per-64t-tile nz flags.
//   Prefix-zero skip: suffix product monotone in t -> zero tiles are a prefix;
//   start MFMA loop at first active tile (bitwise identical; correct even if
//   interior zeros occurred, they'd just be processed as zero work).
//   Active tiles: stage Y = diag(sqrt(a)) X directly from fp32 x (transposed
//   f16 LDS write; x no longer pre-rounded -> strictly fewer roundings than
//   the old xTu path). f16 MFMA 32x32x16, 4 waves x quadrants.
//   Writes FINAL G (no ks partials), svp via register accum + LDS reduce,
//   fall/suma.
// ---------------------------------------------------------------------------
__global__ __launch_bounds__(256, 1) void gscan_kernel(
    const float* __restrict__ x, const float* __restrict__ fw,
    const float* __restrict__ router, const int* __restrict__ mem_id,
    float* __restrict__ G, float* __restrict__ svp,
    float* __restrict__ fallp, float* __restrict__ sumap)
{
    __shared__ ushort sY[128][BKP];      // 22.5 KB scaled tile
    __shared__ f16x2  sQA[S / 2];        // 4 KB sqrt(a) for full S
    __shared__ float  sC[257];           // scan buffer
    __shared__ float  sR4[4];
    __shared__ int    sNZ[NT];           // per-tile nonzero flags
    __shared__ float  sPF[256 * 33];     // 33.8 KB s_vec reduction (+1 pad)

    const int bh = blockIdx.x;
    const int b  = bh >> 3;
    const int tid = threadIdx.x;

    if (tid < NT) sNZ[tid] = 0;

    // ---------------- scan (once per bh) ----------------
    {
        float f[8];
        const float* frow = fw + (size_t)bh * S + tid * 8;
        const float4 fa = *(const float4*)frow;
        const float4 fb = *(const float4*)(frow + 4);
        f[0]=fa.x; f[1]=fa.y; f[2]=fa.z; f[3]=fa.w;
        f[4]=fb.x; f[5]=fb.y; f[6]=fb.z; f[7]=fb.w;

        float p = f[0];
        #pragma unroll
        for (int u = 1; u < 8; ++u) p *= f[u];
        sC[tid] = p;
        __syncthreads();

        for (int off = 1; off < 256; off <<= 1) {
            const float v = (tid + off < 256) ? sC[tid + off] : 1.f;
            __syncthreads();
            sC[tid] *= v;
            __syncthreads();
        }
        const float E = (tid < 255) ? sC[tid + 1] : 1.f;
        const int mid = mem_id[0];

        float aa[8];
        float s = 1.f;
        #pragma unroll
        for (int u = 7; u >= 0; --u) { aa[u] = s * E; s *= f[u]; }

        float avv[8];
        float lsum = 0.f;
        #pragma unroll
        for (int u = 0; u < 8; ++u) {
            const int t = tid * 8 + u;
            const float w = router[((size_t)(b * S) + t) * NM + mid];
            avv[u] = aa[u] * w;
            lsum += avv[u];
        }
        bool nz = false;
        #pragma unroll
        for (int pq = 0; pq < 4; ++pq) {
            f16x2 qp;
            qp.x = (_Float16)sqrtf(avv[2 * pq]);
            qp.y = (_Float16)sqrtf(avv[2 * pq + 1]);
            sQA[tid * 4 + pq] = qp;
            nz = nz || (qp.x != (_Float16)0.f) || (qp.y != (_Float16)0.f);
        }
        if (nz) sNZ[tid >> 3] = 1;       // tile = (tid*8)/64; benign race

        for (int off = 32; off; off >>= 1) lsum += __shfl_down(lsum, off);
        if ((tid & 63) == 0) sR4[tid >> 6] = lsum;
        __syncthreads();
        if (tid == 0) {
            sumap[bh] = sR4[0] + sR4[1] + sR4[2] + sR4[3];
            fallp[bh] = sC[0];
        }
    }
    __syncthreads();

    int nzmask = 0;
    #pragma unroll
    for (int tt = 0; tt < NT; ++tt) nzmask |= (sNZ[tt] ? 1 : 0) << tt;
    const int itStart = (nzmask != 0) ? __builtin_ctz(nzmask) : NT;  // uniform

    // ---------------- MFMA over active tail ----------------
    const int lane = tid & 63, wid = tid >> 6;
    const int wrow = wid >> 1, wcol = wid & 1;
    const int m = lane & 31, half = lane >> 5;
    const int st_t = tid >> 2;          // staging: row t (0..63)
    const int st_q = tid & 3;           // staging: 32-col block
    const _Float16* sqaf = (const _Float16*)sQA;

    float sv[32];
    #pragma unroll
    for (int j = 0; j < 32; ++j) sv[j] = 0.f;
    f32x16 acc00 = {}, acc01 = {}, acc10 = {}, acc11 = {};

    for (int it = itStart; it < NT; ++it) {
        const int t0 = it * BK;
        const float ats = (float)sqaf[t0 + st_t];   // sqrt(a_t), f16-rounded
        const float* xr = x + ((size_t)(b * S) + t0 + st_t) * D + st_q * 32;

        #pragma unroll
        for (int j = 0; j < 8; ++j) {
            const float4 xv = *(const float4*)&xr[j * 4];
            const _Float16 y0 = (_Float16)(xv.x * ats);
            const _Float16 y1 = (_Float16)(xv.y * ats);
            const _Float16 y2 = (_Float16)(xv.z * ats);
            const _Float16 y3 = (_Float16)(xv.w * ats);
            const int d0 = st_q * 32 + j * 4;
            *(_Float16*)&sY[d0 + 0][st_t] = y0;
            *(_Float16*)&sY[d0 + 1][st_t] = y1;
            *(_Float16*)&sY[d0 + 2][st_t] = y2;
            *(_Float16*)&sY[d0 + 3][st_t] = y3;
            // s_vec partial: a_t * x = sqrt(a)*y (y carries MFMA's rounding)
            sv[j * 4 + 0] += (float)y0 * ats;
            sv[j * 4 + 1] += (float)y1 * ats;
            sv[j * 4 + 2] += (float)y2 * ats;
            sv[j * 4 + 3] += (float)y3 * ats;
        }
        __syncthreads();   // staging visible

        #pragma unroll
        for (int kstep = 0; kstep < 4; ++kstep) {
            const int koff = kstep * 16 + half * 8;
            const f16x8 a0 = *(const f16x8*)&sY[wrow * 64 +      m][koff];
            const f16x8 a1 = *(const f16x8*)&sY[wrow * 64 + 32 + m][koff];
            const f16x8 b0 = *(const f16x8*)&sY[wcol * 64 +      m][koff];
            const f16x8 b1 = *(const f16x8*)&sY[wcol * 64 + 32 + m][koff];
            acc00 = __builtin_amdgcn_mfma_f32_32x32x16_f16(a0, b0, acc00, 0, 0, 0);
            acc01 = __builtin_amdgcn_mfma_f32_32x32x16_f16(a0, b1, acc01, 0, 0, 0);
            acc10 = __builtin_amdgcn_mfma_f32_32x32x16_f16(a1, b0, acc10, 0, 0, 0);
            acc11 = __builtin_amdgcn_mfma_f32_32x32x16_f16(a1, b1, acc11, 0, 0, 0);
        }
        __syncthreads();   // MFMA reads done before next staging overwrite
    }

    // C/D layout (m74/m101): col = lane&31, row = (r&3)+8*(r>>2)+4*half
    float* gp = G + (size_t)bh * (D * D);
    #pragma unroll
    for (int rg = 0; rg < 16; ++rg) {
        const int rowl = (rg & 3) + 8 * (rg >> 2) + 4 * half;
        gp[(wrow * 64 +      rowl) * D + wcol * 64 +      m] = acc00[rg];
        gp[(wrow * 64 +      rowl) * D + wcol * 64 + 32 + m] = acc01[rg];
        gp[(wrow * 64 + 32 + rowl) * D + wcol * 64 +      m] = acc10[rg];
        gp[(wrow * 64 + 32 + rowl) * D + wcol * 64 + 32 + m] = acc11[rg];
    }

    // ---------------- s_vec reduction: (st_t, st_q) partials -> d ----------
    #pragma unroll
    for (int j = 0; j < 32; ++j) sPF[tid * 33 + j] = sv[j];
    __syncthreads();
    if (tid < 128) {
        const int q = tid >> 5, dl = tid & 31;   // d = q*32 + dl = tid
        float s = 0.f;
        for (int tt = 0; tt < 64; ++tt)
            s += sPF[(tt * 4 + q) * 33 + dl];
        svp[(size_t)bh * D + tid] = s;
    }
}

// ---------------------------------------------------------------------------
// final: per (bh, col-half): C = Wk^T (G Wv) + u*bv^T + bk*w^T + suma*bk*bv^T
// + fall*M0. fp32 VALU; G symmetry -> all LDS reads row-major float4.
// Single G / svp (no partials).
// ---------------------------------------------------------------------------
__global__ __launch_bounds__(256, 1) void final_kernel(
    const float* __restrict__ G, const float* __restrict__ Wk,
    const float* __restrict__ bk, const float* __restrict__ Wv,
    const float* __restrict__ bv, const float* __restrict__ svp,
    const float* __restrict__ fallp, const float* __restrict__ sumap,
    const float* __restrict__ M0, float* __restrict__ out)
{
    __shared__ float sA[128][132];
    __shared__ float sB[128][132];
    __shared__ float sSv[128];

    const int bh = blockIdx.x >> 1, hf = blockIdx.x & 1;
    const int h  = bh & 7;
    const int tid = threadIdx.x;

    #pragma unroll
    for (int q = 0; q < 16; ++q) {
        const int flat = q * 256 + tid;
        const int row = flat >> 5, c4 = (flat & 31) * 4;
        *(float4*)&sA[row][c4] =
            *(const float4*)&G[(size_t)bh * (D * D) + row * D + c4];
    }
    #pragma unroll
    for (int q = 0; q < 8; ++q) {
        const int flat = q * 256 + tid;
        const int l = flat >> 4, c4 = (flat & 15) * 4;
        *(float4*)&sB[l][c4] =
            *(const float4*)&Wv[(size_t)l * (D * H) + h * D + hf * 64 + c4];
    }
    if (tid < 128) sSv[tid] = svp[(size_t)bh * D + tid];
    __syncthreads();

    const int r0 = (tid >> 3) * 4, c0 = (tid & 7) * 8;

    float P[4][8] = {};
    float wv8[8] = {};
    for (int l = 0; l < 128; ++l) {
        const float4 g  = *(const float4*)&sA[l][r0];
        const float4 w0 = *(const float4*)&sB[l][c0];
        const float4 w1 = *(const float4*)&sB[l][c0 + 4];
        const float sl = sSv[l];
        const float gg[4] = {g.x, g.y, g.z, g.w};
        const float ww[8] = {w0.x,w0.y,w0.z,w0.w,w1.x,w1.y,w1.z,w1.w};
        #pragma unroll
        for (int dr = 0; dr < 4; ++dr)
            #pragma unroll
            for (int dc = 0; dc < 8; ++dc) P[dr][dc] += gg[dr] * ww[dc];
        #pragma unroll
        for (int dc = 0; dc < 8; ++dc) wv8[dc] += sl * ww[dc];
    }
    __syncthreads();

    #pragma unroll
    for (int dr = 0; dr < 4; ++dr) {
        *(float4*)&sA[r0 + dr][c0]     = make_float4(P[dr][0], P[dr][1], P[dr][2], P[dr][3]);
        *(float4*)&sA[r0 + dr][c0 + 4] = make_float4(P[dr][4], P[dr][5], P[dr][6], P[dr][7]);
    }
    #pragma unroll
    for (int q = 0; q < 16; ++q) {
        const int flat = q * 256 + tid;
        const int k = flat >> 5, c4 = (flat & 31) * 4;
        *(float4*)&sB[k][c4] = *(const float4*)&Wk[(size_t)k * (D * H) + h * D + c4];
    }
    __syncthreads();

    float C[4][8] = {};
    float u4[4] = {};
    for (int k = 0; k < 128; ++k) {
        const float4 wk = *(const float4*)&sB[k][r0];
        const float4 p0 = *(const float4*)&sA[k][c0];
        const float4 p1 = *(const float4*)&sA[k][c0 + 4];
        const float svk = sSv[k];
        const float wkk[4] = {wk.x, wk.y, wk.z, wk.w};
        const float pp[8] = {p0.x,p0.y,p0.z,p0.w,p1.x,p1.y,p1.z,p1.w};
        #pragma unroll
        for (int di = 0; di < 4; ++di) {
            #pragma unroll
            for (int dc = 0; dc < 8; ++dc) C[di][dc] += wkk[di] * pp[dc];
            u4[di] += wkk[di] * svk;
        }
    }

    const float fallv = fallp[bh], sumav = sumap[bh];
    float bkv[4], bvv[8];
    #pragma unroll
    for (int di = 0; di < 4; ++di) bkv[di] = bk[h * D + r0 + di];
    #pragma unroll
    for (int dc = 0; dc < 8; ++dc) bvv[dc] = bv[h * D + hf * 64 + c0 + dc];

    const float* m0p = M0 + (size_t)bh * (D * D);
    float* op = out + (size_t)bh * (D * D);
    #pragma unroll
    for (int di = 0; di < 4; ++di)
        #pragma unroll
        for (int dc = 0; dc < 8; ++dc) {
            const size_t idx = (size_t)(r0 + di) * D + hf * 64 + c0 + dc;
            op[idx] = C[di][dc] + u4[di] * bvv[dc] + bkv[di] * wv8[dc]
                    + sumav * bkv[di] * bvv[dc] + fallv * m0p[idx];
        }
}

extern "C" void kernel_launch(void* const* d_in, const int* in_sizes, int n_in,
                              void* d_out, int out_size, void* d_ws, size_t ws_size,
                              hipStream_t stream) {
    const float* x      = (const float*)d_in[0];
    const float* M0     = (const float*)d_in[1];
    const float* router = (const float*)d_in[2];
    const int*   mem_id = (const int*)d_in[3];
    const float* Wk     = (const float*)d_in[4];
    const float* bk     = (const float*)d_in[5];
    const float* Wv     = (const float*)d_in[6];
    const float* bv     = (const float*)d_in[7];
    const float* Wf     = (const float*)d_in[8];
    const float* bf     = (const float*)d_in[9];
    float* out = (float*)d_out;

    char* ws = (char*)d_ws;
    float* fw   = (float*)ws;                                  // 1 MB   f gates
    float* svp  = (float*)(ws + (1u << 20));                   // 64 KB  s_vec
    float* fall = (float*)(ws + (1u << 20) + (256u << 10));    // 512 B
    float* suma = (float*)(ws + (1u << 20) + (256u << 10) + 4096);
    float* G    = (float*)(ws + (2u << 20));                   // 8 MB   G (final)

    f_kernel<<<256, 256, 0, stream>>>(x, Wf, bf, fw);
    gscan_kernel<<<B * H, 256, 0, stream>>>(x, fw, router, mem_id,
                                            G, svp, fall, suma);
    final_kernel<<<2 * B * H, 256, 0, stream>>>(G, Wk, bk, Wv, bv, svp,
                                                fall, suma, M0, out);
}